// Round 4
// baseline (560.192 us; speedup 1.0000x reference)
//
#include <hip/hip_runtime.h>
#include <cfloat>

#define BB 64
#define NN 1024
#define MM 128
#define DD 256
#define MASKV (-1e30f)

typedef __attribute__((ext_vector_type(8))) short bf16x8;
typedef __attribute__((ext_vector_type(16))) float f32x16;

__device__ __forceinline__ unsigned short f2bf(float x) {
  union { float f; unsigned int u; } v; v.f = x;
  unsigned int r = v.u + 0x7fffu + ((v.u >> 16) & 1u);   // round-to-nearest-even
  return (unsigned short)(r >> 16);
}
__device__ __forceinline__ float bf2f(unsigned short h) {
  union { float f; unsigned int u; } v; v.u = ((unsigned int)h) << 16;
  return v.f;
}
__device__ __forceinline__ void split8(const float* xs, uint4* hv, uint4* lv) {
  unsigned hp[4], lp[4];
  #pragma unroll
  for (int p = 0; p < 4; p++) {
    unsigned short h0 = f2bf(xs[2 * p]), h1 = f2bf(xs[2 * p + 1]);
    unsigned short g0 = f2bf(xs[2 * p] - bf2f(h0));
    unsigned short g1 = f2bf(xs[2 * p + 1] - bf2f(h1));
    hp[p] = (unsigned)h0 | ((unsigned)h1 << 16);
    lp[p] = (unsigned)g0 | ((unsigned)g1 << 16);
  }
  *hv = make_uint4(hp[0], hp[1], hp[2], hp[3]);
  *lv = make_uint4(lp[0], lp[1], lp[2], lp[3]);
}
__device__ __forceinline__ bf16x8 u2b(uint4 u) {
  union { uint4 a; bf16x8 b; } x; x.a = u; return x.b;
}

// ---------------------------------------------------------------------------
// K1: sub0[b,n] = c[b,n,:].w0 ; qtermM[b,m] = q[b,m,:].w1 + bias[m] + MASK*(1-qm)
// ---------------------------------------------------------------------------
__global__ __launch_bounds__(256) void k_dots(
    const float* __restrict__ c, const float* __restrict__ q,
    const int* __restrict__ qmask,
    const float* __restrict__ w0, const float* __restrict__ w1,
    const float* __restrict__ bias,
    float* __restrict__ sub0, float* __restrict__ qtermM) {
  int wave = (blockIdx.x * blockDim.x + threadIdx.x) >> 6;
  int lane = threadIdx.x & 63;
  const int total = BB * NN + BB * MM;
  if (wave >= total) return;
  const float* row;
  const float* w;
  if (wave < BB * NN) { row = c + (size_t)wave * DD; w = w0; }
  else                { row = q + (size_t)(wave - BB * NN) * DD; w = w1; }
  float4 v  = *(const float4*)(row + lane * 4);
  float4 wv = *(const float4*)(w   + lane * 4);
  float s = v.x * wv.x + v.y * wv.y + v.z * wv.z + v.w * wv.w;
  #pragma unroll
  for (int off = 32; off > 0; off >>= 1) s += __shfl_xor(s, off, 64);
  if (lane == 0) {
    if (wave < BB * NN) {
      sub0[wave] = s;
    } else {
      int r = wave - BB * NN;
      int m = r & (MM - 1);
      qtermM[r] = s + bias[m] + (qmask[r] ? 0.0f : MASKV);
    }
  }
}

// zero colsum (ws is poisoned 0xAA each call)
__global__ __launch_bounds__(256) void k_zero(float* __restrict__ p) {
  p[blockIdx.x * 256 + threadIdx.x] = 0.0f;
}

// ---------------------------------------------------------------------------
// K_pack: build MFMA B-fragment tensors in bf16 hi/lo from a [M][D] f32 src.
// dst elem offset = (b*32768 + ((f*8+ks)*64 + lane)*8 + j), value =
// sum_p src[p][m][d] * (colsum ? 1/colsum[m] : 1), m=ks*16+(lane>>5)*8+j,
// d=f*32+(lane&31).  Loads are 2x128B coalesced per wave instruction.
// grid (4 dchunks, BB). Used for q (nparts=1) and Apart (nparts=4, scaled).
// ---------------------------------------------------------------------------
__global__ __launch_bounds__(256) void k_pack(
    const float* __restrict__ src, int nparts, int pstride,
    const float* __restrict__ colsum,
    unsigned short* __restrict__ dsth, unsigned short* __restrict__ dstl) {
  const int dchunk = blockIdx.x;
  const int b = blockIdx.y;
  const int t = threadIdx.x;
  const int col = t & 31;
  const int lh = (t >> 5) & 1;
  const int wq = t >> 6;                 // 0..3
  const float* sb = src + (size_t)b * MM * DD;
  #pragma unroll
  for (int i = 0; i < 4; i++) {
    int u = i * 4 + wq;                  // 0..15
    int f_local = u >> 3, ks = u & 7;
    int f = dchunk * 2 + f_local;
    int d = f * 32 + col;
    float ys[8];
    #pragma unroll
    for (int j = 0; j < 8; j++) {
      int m = ks * 16 + lh * 8 + j;
      float v = sb[(size_t)m * DD + d];
      for (int p = 1; p < nparts; p++) v += sb[(size_t)p * pstride + (size_t)m * DD + d];
      if (colsum) v *= 1.0f / colsum[b * MM + m];
      ys[j] = v;
    }
    uint4 hv, lv;
    split8(ys, &hv, &lv);
    size_t off = (size_t)b * 32768 + (size_t)(((f * 8 + ks) * 64) + lh * 32 + col) * 8;
    *(uint4*)(dsth + off) = hv;
    *(uint4*)(dstl + off) = lv;
  }
}

// ---------------------------------------------------------------------------
// K2 (MFMA): sub2 tile GEMM via bf16x3 split (hi*hi + hi*lo + lo*hi),
// 128n x 128m per block, K chunks of 64, mfma_f32_32x32x16_bf16.
// Fused row softmax (over m) -> S_; E emitted TRANSPOSED as bf16 hi/lo
// (EThi/ETlo[b][m][n]) for the MFMA k_colA consumer; colsum via atomics.
// acc C/D layout: col = lane&31, row = (reg&3) + 8*(reg>>2) + 4*(lane>>5).
// ---------------------------------------------------------------------------
__global__ __launch_bounds__(256) void k_score(
    const float* __restrict__ c, const float* __restrict__ q,
    const int* __restrict__ cmask, const float* __restrict__ wm,
    const float* __restrict__ sub0, const float* __restrict__ qtermM,
    float* __restrict__ S_,
    unsigned short* __restrict__ EThi, unsigned short* __restrict__ ETlo,
    float* __restrict__ colsum) {
  __shared__ unsigned short cwh[128 * 64];   // 16 KB each, 64 KB total
  __shared__ unsigned short cwl[128 * 64];
  __shared__ unsigned short qhi[128 * 64];
  __shared__ unsigned short qlo[128 * 64];
  const int b = blockIdx.y;
  const int n0 = blockIdx.x * 128;
  const int t = threadIdx.x;
  const int w = t >> 6;          // wave id: n rows [w*32, w*32+32)
  const int l = t & 63;
  const int l31 = l & 31;
  const int lh = l >> 5;

  f32x16 acc[4];
  #pragma unroll
  for (int mb = 0; mb < 4; mb++)
    #pragma unroll
    for (int i = 0; i < 16; i++) acc[mb][i] = 0.0f;

  for (int k0 = 0; k0 < DD; k0 += 64) {
    __syncthreads();
    #pragma unroll
    for (int g = 0; g < 4; g++) {
      int lin = t + g * 256;           // 0..1023
      int row = lin >> 3;              // 0..127
      int kg  = (lin & 7) * 8;         // 0..56
      unsigned boff = (unsigned)(row * 128 + ((kg * 2) ^ ((row & 7) << 4)));
      float4 w0v = *(const float4*)(wm + k0 + kg);
      float4 w1v = *(const float4*)(wm + k0 + kg + 4);
      const float* cp = c + (size_t)(b * NN + n0 + row) * DD + k0 + kg;
      float4 a0 = *(const float4*)cp;
      float4 a1 = *(const float4*)(cp + 4);
      float xs[8] = {a0.x * w0v.x, a0.y * w0v.y, a0.z * w0v.z, a0.w * w0v.w,
                     a1.x * w1v.x, a1.y * w1v.y, a1.z * w1v.z, a1.w * w1v.w};
      uint4 hv, lv;
      split8(xs, &hv, &lv);
      *(uint4*)((char*)cwh + boff) = hv;
      *(uint4*)((char*)cwl + boff) = lv;
      const float* qp = q + (size_t)(b * MM + row) * DD + k0 + kg;
      float4 b0 = *(const float4*)qp;
      float4 b1 = *(const float4*)(qp + 4);
      float ys[8] = {b0.x, b0.y, b0.z, b0.w, b1.x, b1.y, b1.z, b1.w};
      split8(ys, &hv, &lv);
      *(uint4*)((char*)qhi + boff) = hv;
      *(uint4*)((char*)qlo + boff) = lv;
    }
    __syncthreads();
    #pragma unroll
    for (int ks = 0; ks < 64; ks += 16) {
      int ak = ks + lh * 8;                        // 8 consecutive k per lane
      unsigned arow = (unsigned)(w * 32 + l31);
      unsigned aoff = arow * 128 + (((unsigned)(ak * 2)) ^ ((arow & 7) << 4));
      bf16x8 ah = *(const bf16x8*)((const char*)cwh + aoff);
      bf16x8 al = *(const bf16x8*)((const char*)cwl + aoff);
      #pragma unroll
      for (int mb = 0; mb < 4; mb++) {
        unsigned brow = (unsigned)(mb * 32 + l31);
        unsigned boff2 = brow * 128 + (((unsigned)(ak * 2)) ^ ((brow & 7) << 4));
        bf16x8 bh = *(const bf16x8*)((const char*)qhi + boff2);
        bf16x8 bl = *(const bf16x8*)((const char*)qlo + boff2);
        acc[mb] = __builtin_amdgcn_mfma_f32_32x32x16_bf16(ah, bh, acc[mb], 0, 0, 0);
        acc[mb] = __builtin_amdgcn_mfma_f32_32x32x16_bf16(ah, bl, acc[mb], 0, 0, 0);
        acc[mb] = __builtin_amdgcn_mfma_f32_32x32x16_bf16(al, bh, acc[mb], 0, 0, 0);
      }
    }
  }

  // fused row softmax + ET (bf16 hi/lo, transposed) + colsum
  float qt[4];
  #pragma unroll
  for (int mb = 0; mb < 4; mb++) qt[mb] = qtermM[b * MM + mb * 32 + l31];

  float ps[4] = {0.f, 0.f, 0.f, 0.f};
  // r = 4*g + j -> n-row within wave tile = j + 8*g + 4*lh (j consecutive)
  #pragma unroll
  for (int g = 0; g < 4; g++) {
    float evg[4][4];
    #pragma unroll
    for (int j = 0; j < 4; j++) {
      int r = 4 * g + j;
      int row = j + 8 * g + 4 * lh;
      int gn = n0 + w * 32 + row;
      float s0m = sub0[b * NN + gn] + (cmask[b * NN + gn] ? 0.0f : MASKV);
      float x[4];
      float vmax = -FLT_MAX;
      #pragma unroll
      for (int mb = 0; mb < 4; mb++) { x[mb] = acc[mb][r] + qt[mb]; vmax = fmaxf(vmax, x[mb]); }
      #pragma unroll
      for (int off = 16; off > 0; off >>= 1) vmax = fmaxf(vmax, __shfl_xor(vmax, off, 64));
      float e[4];
      float vsum = 0.0f;
      #pragma unroll
      for (int mb = 0; mb < 4; mb++) { e[mb] = __expf(x[mb] - vmax); vsum += e[mb]; }
      #pragma unroll
      for (int off = 16; off > 0; off >>= 1) vsum += __shfl_xor(vsum, off, 64);
      float inv = 1.0f / vsum;
      size_t base = (size_t)(b * NN + gn) * MM + l31;
      #pragma unroll
      for (int mb = 0; mb < 4; mb++) {
        S_[base + mb * 32] = e[mb] * inv;
        float Ev = __expf(acc[mb][r] + s0m);   // exp(-1e30+x) underflows to 0 exactly
        evg[mb][j] = Ev;
        ps[mb] += Ev;
      }
    }
    // pack 4 consecutive n per (mb) as bf16 hi/lo, store 8B each
    #pragma unroll
    for (int mb = 0; mb < 4; mb++) {
      unsigned short h[4], lo[4];
      #pragma unroll
      for (int j = 0; j < 4; j++) {
        h[j] = f2bf(evg[mb][j]);
        lo[j] = f2bf(evg[mb][j] - bf2f(h[j]));
      }
      size_t off = (size_t)(b * MM + mb * 32 + l31) * NN + n0 + w * 32 + 8 * g + 4 * lh;
      *(uint2*)(EThi + off) = make_uint2((unsigned)h[0] | ((unsigned)h[1] << 16),
                                         (unsigned)h[2] | ((unsigned)h[3] << 16));
      *(uint2*)(ETlo + off) = make_uint2((unsigned)lo[0] | ((unsigned)lo[1] << 16),
                                         (unsigned)lo[2] | ((unsigned)lo[3] << 16));
    }
  }
  #pragma unroll
  for (int mb = 0; mb < 4; mb++) {
    ps[mb] += __shfl_xor(ps[mb], 32, 64);    // combine the two half-wave row sets
    if (lh == 0) atomicAdd(&colsum[b * MM + mb * 32 + l31], ps[mb]);
  }
}

// ---------------------------------------------------------------------------
// K4 (MFMA): Apart[p][b][m][d] = sum_{n in chunk p} ET[m][n] * c[n][d]
// A-op = c^T (rows d, k=n): 8 stride-DD scalar loads (coalesced across lanes)
// + bf16x3 split. B-op = ET (rows m): direct bf16x8 hi/lo loads, no split.
// Reduction over p + 1/colsum + fragment-pack happens in k_pack.
// ---------------------------------------------------------------------------
__global__ __launch_bounds__(512) void k_colA(
    const unsigned short* __restrict__ EThi, const unsigned short* __restrict__ ETlo,
    const float* __restrict__ c, float* __restrict__ Apart) {
  const int p = blockIdx.x;
  const int b = blockIdx.y;
  const int t = threadIdx.x;
  const int w = t >> 6;
  const int l = t & 63;
  const int l31 = l & 31, lh = l >> 5;
  const int d = w * 32 + l31;

  f32x16 acc[4];
  #pragma unroll
  for (int mf = 0; mf < 4; mf++)
    #pragma unroll
    for (int i = 0; i < 16; i++) acc[mf][i] = 0.0f;

  const float* cb = c + (size_t)b * NN * DD + d;
  const size_t etb = (size_t)b * MM * NN + (size_t)p * 256 + lh * 8;

  for (int ks = 0; ks < 16; ks++) {
    int nb = p * 256 + ks * 16 + lh * 8;
    float ys[8];
    #pragma unroll
    for (int j = 0; j < 8; j++) ys[j] = cb[(size_t)(nb + j) * DD];
    uint4 hv, lv;
    split8(ys, &hv, &lv);
    bf16x8 ah = u2b(hv), al = u2b(lv);
    #pragma unroll
    for (int mf = 0; mf < 4; mf++) {
      size_t eoff = etb + (size_t)(mf * 32 + l31) * NN + ks * 16;
      bf16x8 bh = *(const bf16x8*)(EThi + eoff);
      bf16x8 bl = *(const bf16x8*)(ETlo + eoff);
      acc[mf] = __builtin_amdgcn_mfma_f32_32x32x16_bf16(ah, bh, acc[mf], 0, 0, 0);
      acc[mf] = __builtin_amdgcn_mfma_f32_32x32x16_bf16(ah, bl, acc[mf], 0, 0, 0);
      acc[mf] = __builtin_amdgcn_mfma_f32_32x32x16_bf16(al, bh, acc[mf], 0, 0, 0);
    }
  }

  float* ap = Apart + (size_t)p * (BB * MM * DD);
  #pragma unroll
  for (int mf = 0; mf < 4; mf++) {
    size_t rowb = (size_t)(b * MM + mf * 32 + l31) * DD + w * 32 + 4 * lh;
    #pragma unroll
    for (int g = 0; g < 4; g++) {
      float4 o = make_float4(acc[mf][4 * g + 0], acc[mf][4 * g + 1],
                             acc[mf][4 * g + 2], acc[mf][4 * g + 3]);
      *(float4*)(ap + rowb + 8 * g) = o;
    }
  }
}

// ---------------------------------------------------------------------------
// K5 (MFMA): c2q = S_ @ q ; q2c = S_ @ Anorm ; out = [c, c2q, c*c2q, c*q2c]
// B-operands come pre-split/pre-packed in fragment layout (qf*/af*), so the
// inner loop is: 2 dwordx4 (S_) + split + per df {2x bf16x8 loads + 3 MFMA}.
// Waves 0-3: c2q + planes {c, c2q, c*c2q}; waves 4-7: q2c + plane {c*q2c}.
// ---------------------------------------------------------------------------
__global__ __launch_bounds__(512) void k_out(
    const float* __restrict__ c, const float* __restrict__ S_,
    const unsigned short* __restrict__ qfh, const unsigned short* __restrict__ qfl,
    const unsigned short* __restrict__ afh, const unsigned short* __restrict__ afl,
    float* __restrict__ out) {
  const int b = blockIdx.y;
  const int n0 = blockIdx.x * 64;
  const int t = threadIdx.x;
  const int w = t >> 6;            // 0..7
  const int l = t & 63;
  const int l31 = l & 31;
  const int lh = l >> 5;
  const int grp = w >> 2;          // 0: c2q, 1: q2c
  const int wi = w & 3;
  const int nf = wi & 1;           // n-frag (32 rows)
  const int fd0 = (wi >> 1) * 4;   // first d-frag (of 8)

  const unsigned short* Bh = grp ? afh : qfh;
  const unsigned short* Bl = grp ? afl : qfl;
  const size_t fb = (size_t)b * 32768;

  f32x16 acc[4];
  #pragma unroll
  for (int df = 0; df < 4; df++)
    #pragma unroll
    for (int i = 0; i < 16; i++) acc[df][i] = 0.0f;

  const float* srow = S_ + (size_t)(b * NN + n0 + nf * 32 + l31) * MM + lh * 8;

  #pragma unroll 2
  for (int ks = 0; ks < 8; ks++) {
    float4 s0 = *(const float4*)(srow + ks * 16);
    float4 s1 = *(const float4*)(srow + ks * 16 + 4);
    float xs[8] = {s0.x, s0.y, s0.z, s0.w, s1.x, s1.y, s1.z, s1.w};
    uint4 hv, lv;
    split8(xs, &hv, &lv);
    bf16x8 ah = u2b(hv), al = u2b(lv);
    #pragma unroll
    for (int df = 0; df < 4; df++) {
      int f = fd0 + df;
      size_t off = fb + (size_t)(((f * 8 + ks) * 64) + l) * 8;
      bf16x8 bh = *(const bf16x8*)(Bh + off);
      bf16x8 bl = *(const bf16x8*)(Bl + off);
      acc[df] = __builtin_amdgcn_mfma_f32_32x32x16_bf16(ah, bh, acc[df], 0, 0, 0);
      acc[df] = __builtin_amdgcn_mfma_f32_32x32x16_bf16(ah, bl, acc[df], 0, 0, 0);
      acc[df] = __builtin_amdgcn_mfma_f32_32x32x16_bf16(al, bh, acc[df], 0, 0, 0);
    }
  }

  #pragma unroll
  for (int df = 0; df < 4; df++) {
    int d = (fd0 + df) * 32 + l31;
    #pragma unroll
    for (int r = 0; r < 16; r++) {
      int row = (r & 3) + 8 * (r >> 2) + 4 * lh;
      int gn = n0 + nf * 32 + row;
      float v = acc[df][r];
      float cv = c[(size_t)(b * NN + gn) * DD + d];
      size_t ob = (size_t)(b * NN + gn) * (4 * DD) + d;
      if (grp == 0) {
        out[ob]            = cv;
        out[ob + DD]       = v;
        out[ob + 2 * DD]   = cv * v;
      } else {
        out[ob + 3 * DD]   = cv * v;
      }
    }
  }
}

// ---------------------------------------------------------------------------
extern "C" void kernel_launch(void* const* d_in, const int* in_sizes, int n_in,
                              void* d_out, int out_size, void* d_ws, size_t ws_size,
                              hipStream_t stream) {
  const float* c     = (const float*)d_in[0];
  const float* q     = (const float*)d_in[1];
  const int*   cmask = (const int*)d_in[2];
  const int*   qmask = (const int*)d_in[3];
  const float* w0    = (const float*)d_in[4];
  const float* w1    = (const float*)d_in[5];
  const float* wm    = (const float*)d_in[6];
  const float* bias  = (const float*)d_in[7];
  float* out = (float*)d_out;
  float* ws  = (float*)d_ws;

  float* S_     = ws;                                        // 8388608 f
  unsigned short* EThi = (unsigned short*)(ws + 8388608);    // 8388608 u16
  unsigned short* ETlo = (unsigned short*)(ws + 12582912);   // 8388608 u16
  float* Apart  = ws + 16777216;                             // 4 * 2097152 f
  unsigned short* qfh = (unsigned short*)(ws + 25165824);    // 2097152 u16
  unsigned short* qfl = (unsigned short*)(ws + 26214400);
  unsigned short* afh = (unsigned short*)(ws + 27262976);
  unsigned short* afl = (unsigned short*)(ws + 28311552);
  float* sub0   = ws + 29360128;                             // 65536 f
  float* qtermM = ws + 29425664;                             // 8192 f
  float* colsum = ws + 29433856;                             // 8192 f

  k_dots<<<18432, 256, 0, stream>>>(c, q, qmask, w0, w1, bias, sub0, qtermM);
  k_zero<<<32, 256, 0, stream>>>(colsum);
  k_pack<<<dim3(4, BB), 256, 0, stream>>>(q, 1, 0, nullptr, qfh, qfl);
  k_score<<<dim3(8, BB), 256, 0, stream>>>(c, q, cmask, wm, sub0, qtermM, S_, EThi, ETlo, colsum);
  k_colA<<<dim3(4, BB), 512, 0, stream>>>(EThi, ETlo, c, Apart);
  k_pack<<<dim3(4, BB), 256, 0, stream>>>(Apart, 4, BB * MM * DD, colsum, afh, afl);
  k_out<<<dim3(16, BB), 512, 0, stream>>>(c, S_, qfh, qfl, afh, afl, out);
}

// Round 5
// 487.204 us; speedup vs baseline: 1.1498x; 1.1498x over previous
//
#include <hip/hip_runtime.h>
#include <cfloat>

#define BB 64
#define NN 1024
#define MM 128
#define DD 256
#define MASKV (-1e30f)

typedef __attribute__((ext_vector_type(8))) short bf16x8;
typedef __attribute__((ext_vector_type(16))) float f32x16;

__device__ __forceinline__ unsigned short f2bf(float x) {
  union { float f; unsigned int u; } v; v.f = x;
  unsigned int r = v.u + 0x7fffu + ((v.u >> 16) & 1u);   // round-to-nearest-even
  return (unsigned short)(r >> 16);
}
__device__ __forceinline__ float bf2f(unsigned short h) {
  union { float f; unsigned int u; } v; v.u = ((unsigned int)h) << 16;
  return v.f;
}
__device__ __forceinline__ void split8(const float* xs, uint4* hv, uint4* lv) {
  unsigned hp[4], lp[4];
  #pragma unroll
  for (int p = 0; p < 4; p++) {
    unsigned short h0 = f2bf(xs[2 * p]), h1 = f2bf(xs[2 * p + 1]);
    unsigned short g0 = f2bf(xs[2 * p] - bf2f(h0));
    unsigned short g1 = f2bf(xs[2 * p + 1] - bf2f(h1));
    hp[p] = (unsigned)h0 | ((unsigned)h1 << 16);
    lp[p] = (unsigned)g0 | ((unsigned)g1 << 16);
  }
  *hv = make_uint4(hp[0], hp[1], hp[2], hp[3]);
  *lv = make_uint4(lp[0], lp[1], lp[2], lp[3]);
}
__device__ __forceinline__ bf16x8 u2b(uint4 u) {
  union { uint4 a; bf16x8 b; } x; x.a = u; return x.b;
}

// ---------------------------------------------------------------------------
// K1: sub0[b,n] = c[b,n,:].w0 ; qtermM[b,m] = q[b,m,:].w1 + bias[m] + MASK*(1-qm)
// ---------------------------------------------------------------------------
__global__ __launch_bounds__(256) void k_dots(
    const float* __restrict__ c, const float* __restrict__ q,
    const int* __restrict__ qmask,
    const float* __restrict__ w0, const float* __restrict__ w1,
    const float* __restrict__ bias,
    float* __restrict__ sub0, float* __restrict__ qtermM) {
  int wave = (blockIdx.x * blockDim.x + threadIdx.x) >> 6;
  int lane = threadIdx.x & 63;
  const int total = BB * NN + BB * MM;
  if (wave >= total) return;
  const float* row;
  const float* w;
  if (wave < BB * NN) { row = c + (size_t)wave * DD; w = w0; }
  else                { row = q + (size_t)(wave - BB * NN) * DD; w = w1; }
  float4 v  = *(const float4*)(row + lane * 4);
  float4 wv = *(const float4*)(w   + lane * 4);
  float s = v.x * wv.x + v.y * wv.y + v.z * wv.z + v.w * wv.w;
  #pragma unroll
  for (int off = 32; off > 0; off >>= 1) s += __shfl_xor(s, off, 64);
  if (lane == 0) {
    if (wave < BB * NN) {
      sub0[wave] = s;
    } else {
      int r = wave - BB * NN;
      int m = r & (MM - 1);
      qtermM[r] = s + bias[m] + (qmask[r] ? 0.0f : MASKV);
    }
  }
}

// zero colsum (ws is poisoned 0xAA each call)
__global__ __launch_bounds__(256) void k_zero(float* __restrict__ p) {
  p[blockIdx.x * 256 + threadIdx.x] = 0.0f;
}

// ---------------------------------------------------------------------------
// K_pack_q: q -> MFMA B-fragment bf16 hi/lo.  One (f,ks) combo per wave.
// dst elem off = b*32768 + (u*64+lane)*8 + j, u=f*8+ks;
// value = q[b][ks*16+lh*8+j][f*32+l31].  grid (16, BB) = 1024 blocks.
// ---------------------------------------------------------------------------
__global__ __launch_bounds__(256) void k_pack_q(
    const float* __restrict__ q,
    unsigned short* __restrict__ dsth, unsigned short* __restrict__ dstl) {
  const int b = blockIdx.y;
  const int u = blockIdx.x * 4 + (threadIdx.x >> 6);   // 0..63
  const int f = u >> 3, ks = u & 7;
  const int l = threadIdx.x & 63;
  const int l31 = l & 31, lh = l >> 5;
  const float* sb = q + (size_t)b * MM * DD + (size_t)(ks * 16 + lh * 8) * DD + f * 32 + l31;
  float ys[8];
  #pragma unroll
  for (int j = 0; j < 8; j++) ys[j] = sb[(size_t)j * DD];
  uint4 hv, lv;
  split8(ys, &hv, &lv);
  size_t off = (size_t)b * 32768 + (size_t)(u * 64 + l) * 8;
  *(uint4*)(dsth + off) = hv;
  *(uint4*)(dstl + off) = lv;
}

// ---------------------------------------------------------------------------
// K_pack_a: Anorm = (sum_p Apart[p]) / colsum -> B-fragment bf16 hi/lo.
// Same layout as k_pack_q.  grid (16, BB).
// ---------------------------------------------------------------------------
__global__ __launch_bounds__(256) void k_pack_a(
    const float* __restrict__ Apart, const float* __restrict__ colsum,
    unsigned short* __restrict__ dsth, unsigned short* __restrict__ dstl) {
  const int b = blockIdx.y;
  const int u = blockIdx.x * 4 + (threadIdx.x >> 6);
  const int f = u >> 3, ks = u & 7;
  const int l = threadIdx.x & 63;
  const int l31 = l & 31, lh = l >> 5;
  const int m0 = ks * 16 + lh * 8;
  const size_t P = (size_t)BB * MM * DD;
  const float* sb = Apart + (size_t)b * MM * DD + (size_t)m0 * DD + f * 32 + l31;
  float ys[8];
  #pragma unroll
  for (int j = 0; j < 8; j++) {
    float v = sb[(size_t)j * DD] + sb[P + (size_t)j * DD] +
              sb[2 * P + (size_t)j * DD] + sb[3 * P + (size_t)j * DD];
    ys[j] = v * (1.0f / colsum[b * MM + m0 + j]);
  }
  uint4 hv, lv;
  split8(ys, &hv, &lv);
  size_t off = (size_t)b * 32768 + (size_t)(u * 64 + l) * 8;
  *(uint4*)(dsth + off) = hv;
  *(uint4*)(dstl + off) = lv;
}

// ---------------------------------------------------------------------------
// K2 (MFMA): sub2 tile GEMM via bf16x3 split (hi*hi + hi*lo + lo*hi),
// 128n x 128m per block, K chunks of 64, mfma_f32_32x32x16_bf16.
// Fused row softmax -> S_ (f32, coalesced); E emitted TRANSPOSED bf16 hi/lo
// via a swizzled LDS tile (reusing staging LDS) -> coalesced global stores.
// acc C/D layout: col = lane&31, row = (reg&3) + 8*(reg>>2) + 4*(lane>>5).
// ---------------------------------------------------------------------------
__global__ __launch_bounds__(256) void k_score(
    const float* __restrict__ c, const float* __restrict__ q,
    const int* __restrict__ cmask, const float* __restrict__ wm,
    const float* __restrict__ sub0, const float* __restrict__ qtermM,
    float* __restrict__ S_,
    unsigned short* __restrict__ EThi, unsigned short* __restrict__ ETlo,
    float* __restrict__ colsum) {
  __shared__ unsigned short smem[32768];     // 64 KB, aliased below
  unsigned short* cwh = smem;                // [128][64] staging
  unsigned short* cwl = smem + 8192;
  unsigned short* qhi = smem + 16384;
  unsigned short* qlo = smem + 24576;
  const int b = blockIdx.y;
  const int n0 = blockIdx.x * 128;
  const int t = threadIdx.x;
  const int w = t >> 6;          // wave id: n rows [w*32, w*32+32)
  const int l = t & 63;
  const int l31 = l & 31;
  const int lh = l >> 5;

  f32x16 acc[4];
  #pragma unroll
  for (int mb = 0; mb < 4; mb++)
    #pragma unroll
    for (int i = 0; i < 16; i++) acc[mb][i] = 0.0f;

  for (int k0 = 0; k0 < DD; k0 += 64) {
    __syncthreads();
    #pragma unroll
    for (int g = 0; g < 4; g++) {
      int lin = t + g * 256;           // 0..1023
      int row = lin >> 3;              // 0..127
      int kg  = (lin & 7) * 8;         // 0..56
      unsigned boff = (unsigned)(row * 128 + ((kg * 2) ^ ((row & 7) << 4)));
      float4 w0v = *(const float4*)(wm + k0 + kg);
      float4 w1v = *(const float4*)(wm + k0 + kg + 4);
      const float* cp = c + (size_t)(b * NN + n0 + row) * DD + k0 + kg;
      float4 a0 = *(const float4*)cp;
      float4 a1 = *(const float4*)(cp + 4);
      float xs[8] = {a0.x * w0v.x, a0.y * w0v.y, a0.z * w0v.z, a0.w * w0v.w,
                     a1.x * w1v.x, a1.y * w1v.y, a1.z * w1v.z, a1.w * w1v.w};
      uint4 hv, lv;
      split8(xs, &hv, &lv);
      *(uint4*)((char*)cwh + boff) = hv;
      *(uint4*)((char*)cwl + boff) = lv;
      const float* qp = q + (size_t)(b * MM + row) * DD + k0 + kg;
      float4 b0 = *(const float4*)qp;
      float4 b1 = *(const float4*)(qp + 4);
      float ys[8] = {b0.x, b0.y, b0.z, b0.w, b1.x, b1.y, b1.z, b1.w};
      split8(ys, &hv, &lv);
      *(uint4*)((char*)qhi + boff) = hv;
      *(uint4*)((char*)qlo + boff) = lv;
    }
    __syncthreads();
    #pragma unroll
    for (int ks = 0; ks < 64; ks += 16) {
      int ak = ks + lh * 8;                        // 8 consecutive k per lane
      unsigned arow = (unsigned)(w * 32 + l31);
      unsigned aoff = arow * 128 + (((unsigned)(ak * 2)) ^ ((arow & 7) << 4));
      bf16x8 ah = *(const bf16x8*)((const char*)cwh + aoff);
      bf16x8 al = *(const bf16x8*)((const char*)cwl + aoff);
      #pragma unroll
      for (int mb = 0; mb < 4; mb++) {
        unsigned brow = (unsigned)(mb * 32 + l31);
        unsigned boff2 = brow * 128 + (((unsigned)(ak * 2)) ^ ((brow & 7) << 4));
        bf16x8 bh = *(const bf16x8*)((const char*)qhi + boff2);
        bf16x8 bl = *(const bf16x8*)((const char*)qlo + boff2);
        acc[mb] = __builtin_amdgcn_mfma_f32_32x32x16_bf16(ah, bh, acc[mb], 0, 0, 0);
        acc[mb] = __builtin_amdgcn_mfma_f32_32x32x16_bf16(ah, bl, acc[mb], 0, 0, 0);
        acc[mb] = __builtin_amdgcn_mfma_f32_32x32x16_bf16(al, bh, acc[mb], 0, 0, 0);
      }
    }
  }

  // --- softmax + E; staging LDS is dead from here -> reuse as ET tile ---
  // eth/etl: [m=0..127][nloc=0..127] bf16, row = 256 B, byte swizzle:
  //   addr = m*256 + ((nloc*2) ^ ((m&15)<<4))   (16B-block XOR, 8B-safe)
  unsigned short* eth = smem;            // 32 KB
  unsigned short* etl = smem + 16384;    // 32 KB
  __syncthreads();                        // all waves done with staged MFMA reads

  float qt[4];
  #pragma unroll
  for (int mb = 0; mb < 4; mb++) qt[mb] = qtermM[b * MM + mb * 32 + l31];

  float ps[4] = {0.f, 0.f, 0.f, 0.f};
  // r = 4*g + j -> n-row within wave tile = j + 8*g + 4*lh (j consecutive)
  #pragma unroll
  for (int g = 0; g < 4; g++) {
    float evg[4][4];
    #pragma unroll
    for (int j = 0; j < 4; j++) {
      int r = 4 * g + j;
      int row = j + 8 * g + 4 * lh;
      int gn = n0 + w * 32 + row;
      float s0m = sub0[b * NN + gn] + (cmask[b * NN + gn] ? 0.0f : MASKV);
      float x[4];
      float vmax = -FLT_MAX;
      #pragma unroll
      for (int mb = 0; mb < 4; mb++) { x[mb] = acc[mb][r] + qt[mb]; vmax = fmaxf(vmax, x[mb]); }
      #pragma unroll
      for (int off = 16; off > 0; off >>= 1) vmax = fmaxf(vmax, __shfl_xor(vmax, off, 64));
      float e[4];
      float vsum = 0.0f;
      #pragma unroll
      for (int mb = 0; mb < 4; mb++) { e[mb] = __expf(x[mb] - vmax); vsum += e[mb]; }
      #pragma unroll
      for (int off = 16; off > 0; off >>= 1) vsum += __shfl_xor(vsum, off, 64);
      float inv = 1.0f / vsum;
      size_t base = (size_t)(b * NN + gn) * MM + l31;
      #pragma unroll
      for (int mb = 0; mb < 4; mb++) {
        S_[base + mb * 32] = e[mb] * inv;
        float Ev = __expf(acc[mb][r] + s0m);   // exp(-1e30+x) underflows to 0 exactly
        evg[mb][j] = Ev;
        ps[mb] += Ev;
      }
    }
    // write 4 consecutive n per (mb) into swizzled LDS ET tile (8B each)
    int nloc = w * 32 + 8 * g + 4 * lh;
    #pragma unroll
    for (int mb = 0; mb < 4; mb++) {
      int m = mb * 32 + l31;
      unsigned short h[4], lo[4];
      #pragma unroll
      for (int j = 0; j < 4; j++) {
        h[j] = f2bf(evg[mb][j]);
        lo[j] = f2bf(evg[mb][j] - bf2f(h[j]));
      }
      unsigned addr = (unsigned)(m * 256 + ((nloc * 2) ^ ((m & 15) << 4)));
      *(uint2*)((char*)eth + addr) = make_uint2(
          (unsigned)h[0] | ((unsigned)h[1] << 16),
          (unsigned)h[2] | ((unsigned)h[3] << 16));
      *(uint2*)((char*)etl + addr) = make_uint2(
          (unsigned)lo[0] | ((unsigned)lo[1] << 16),
          (unsigned)lo[2] | ((unsigned)lo[3] << 16));
    }
  }
  #pragma unroll
  for (int mb = 0; mb < 4; mb++) {
    ps[mb] += __shfl_xor(ps[mb], 32, 64);    // combine the two half-wave row sets
    if (lh == 0) atomicAdd(&colsum[b * MM + mb * 32 + l31], ps[mb]);
  }

  __syncthreads();
  // cooperative coalesced ET store: wave = 4 m-rows x 16 chunks of 16B
  {
    int chunk = t & 15;                    // 16B chunk within 256B row
    int mrow0 = t >> 4;                    // 0..15
    #pragma unroll
    for (int it = 0; it < 8; it++) {
      int m = it * 16 + mrow0;
      int sw = (chunk * 16) ^ ((m & 15) << 4);
      uint4 vh = *(const uint4*)((const char*)eth + m * 256 + sw);
      uint4 vl = *(const uint4*)((const char*)etl + m * 256 + sw);
      size_t gb = (size_t)(b * MM + m) * NN + n0 + chunk * 8;
      *(uint4*)(EThi + gb) = vh;
      *(uint4*)(ETlo + gb) = vl;
    }
  }
}

// ---------------------------------------------------------------------------
// K4 (MFMA): Apart[p][b][m][d] = sum_{n in chunk p} ET[m][n] * c[n][d]
// A-op = c^T (rows d, k=n): 8 stride-DD scalar loads + bf16x3 split.
// B-op = ET (rows m): direct bf16x8 hi/lo loads.
// ---------------------------------------------------------------------------
__global__ __launch_bounds__(512) void k_colA(
    const unsigned short* __restrict__ EThi, const unsigned short* __restrict__ ETlo,
    const float* __restrict__ c, float* __restrict__ Apart) {
  const int p = blockIdx.x;
  const int b = blockIdx.y;
  const int t = threadIdx.x;
  const int w = t >> 6;
  const int l = t & 63;
  const int l31 = l & 31, lh = l >> 5;
  const int d = w * 32 + l31;

  f32x16 acc[4];
  #pragma unroll
  for (int mf = 0; mf < 4; mf++)
    #pragma unroll
    for (int i = 0; i < 16; i++) acc[mf][i] = 0.0f;

  const float* cb = c + (size_t)b * NN * DD + d;
  const size_t etb = (size_t)b * MM * NN + (size_t)p * 256 + lh * 8;

  for (int ks = 0; ks < 16; ks++) {
    int nb = p * 256 + ks * 16 + lh * 8;
    float ys[8];
    #pragma unroll
    for (int j = 0; j < 8; j++) ys[j] = cb[(size_t)(nb + j) * DD];
    uint4 hv, lv;
    split8(ys, &hv, &lv);
    bf16x8 ah = u2b(hv), al = u2b(lv);
    #pragma unroll
    for (int mf = 0; mf < 4; mf++) {
      size_t eoff = etb + (size_t)(mf * 32 + l31) * NN + ks * 16;
      bf16x8 bh = *(const bf16x8*)(EThi + eoff);
      bf16x8 bl = *(const bf16x8*)(ETlo + eoff);
      acc[mf] = __builtin_amdgcn_mfma_f32_32x32x16_bf16(ah, bh, acc[mf], 0, 0, 0);
      acc[mf] = __builtin_amdgcn_mfma_f32_32x32x16_bf16(ah, bl, acc[mf], 0, 0, 0);
      acc[mf] = __builtin_amdgcn_mfma_f32_32x32x16_bf16(al, bh, acc[mf], 0, 0, 0);
    }
  }

  float* ap = Apart + (size_t)p * (BB * MM * DD);
  #pragma unroll
  for (int mf = 0; mf < 4; mf++) {
    size_t rowb = (size_t)(b * MM + mf * 32 + l31) * DD + w * 32 + 4 * lh;
    #pragma unroll
    for (int g = 0; g < 4; g++) {
      float4 o = make_float4(acc[mf][4 * g + 0], acc[mf][4 * g + 1],
                             acc[mf][4 * g + 2], acc[mf][4 * g + 3]);
      *(float4*)(ap + rowb + 8 * g) = o;
    }
  }
}

// ---------------------------------------------------------------------------
// K5 (MFMA): c2q = S_ @ q ; q2c = S_ @ Anorm ; out = [c, c2q, c*c2q, c*q2c]
// Occupancy-oriented: 32-row n-tile, 8 waves; wave w owns d-frag f=w and
// computes BOTH GEMMs (acc=2x16=32 AGPR, one S-split shared, c loaded once,
// all 4 planes written by the same wave). grid (32, BB) = 2048 blocks (2x cap).
// ---------------------------------------------------------------------------
__global__ __launch_bounds__(512, 4) void k_out(
    const float* __restrict__ c, const float* __restrict__ S_,
    const unsigned short* __restrict__ qfh, const unsigned short* __restrict__ qfl,
    const unsigned short* __restrict__ afh, const unsigned short* __restrict__ afl,
    float* __restrict__ out) {
  const int b = blockIdx.y;
  const int n0 = blockIdx.x * 32;
  const int t = threadIdx.x;
  const int w = t >> 6;            // wave id == d-frag f
  const int l = t & 63;
  const int l31 = l & 31;
  const int lh = l >> 5;

  f32x16 acc0, acc1;
  #pragma unroll
  for (int i = 0; i < 16; i++) { acc0[i] = 0.0f; acc1[i] = 0.0f; }

  const float* srow = S_ + (size_t)(b * NN + n0 + l31) * MM + lh * 8;
  const size_t fo = (size_t)b * 32768 + (size_t)(w * 8 * 64 + l) * 8;

  #pragma unroll
  for (int ks = 0; ks < 8; ks++) {
    float4 s0 = *(const float4*)(srow + ks * 16);
    float4 s1 = *(const float4*)(srow + ks * 16 + 4);
    float xs[8] = {s0.x, s0.y, s0.z, s0.w, s1.x, s1.y, s1.z, s1.w};
    uint4 hv, lv;
    split8(xs, &hv, &lv);
    bf16x8 ah = u2b(hv), al = u2b(lv);
    size_t off = fo + (size_t)(ks * 64) * 8;
    bf16x8 qh = *(const bf16x8*)(qfh + off);
    bf16x8 ql = *(const bf16x8*)(qfl + off);
    bf16x8 vh = *(const bf16x8*)(afh + off);
    bf16x8 vl = *(const bf16x8*)(afl + off);
    acc0 = __builtin_amdgcn_mfma_f32_32x32x16_bf16(ah, qh, acc0, 0, 0, 0);
    acc0 = __builtin_amdgcn_mfma_f32_32x32x16_bf16(ah, ql, acc0, 0, 0, 0);
    acc0 = __builtin_amdgcn_mfma_f32_32x32x16_bf16(al, qh, acc0, 0, 0, 0);
    acc1 = __builtin_amdgcn_mfma_f32_32x32x16_bf16(ah, vh, acc1, 0, 0, 0);
    acc1 = __builtin_amdgcn_mfma_f32_32x32x16_bf16(ah, vl, acc1, 0, 0, 0);
    acc1 = __builtin_amdgcn_mfma_f32_32x32x16_bf16(al, vh, acc1, 0, 0, 0);
  }

  const int d = w * 32 + l31;
  #pragma unroll
  for (int r = 0; r < 16; r++) {
    int row = (r & 3) + 8 * (r >> 2) + 4 * lh;
    int gn = n0 + row;
    float cv = c[(size_t)(b * NN + gn) * DD + d];
    size_t ob = (size_t)(b * NN + gn) * (4 * DD) + d;
    float v1 = acc0[r], v3 = acc1[r];
    out[ob]          = cv;
    out[ob + DD]     = v1;
    out[ob + 2 * DD] = cv * v1;
    out[ob + 3 * DD] = cv * v3;
  }
}

// ---------------------------------------------------------------------------
extern "C" void kernel_launch(void* const* d_in, const int* in_sizes, int n_in,
                              void* d_out, int out_size, void* d_ws, size_t ws_size,
                              hipStream_t stream) {
  const float* c     = (const float*)d_in[0];
  const float* q     = (const float*)d_in[1];
  const int*   cmask = (const int*)d_in[2];
  const int*   qmask = (const int*)d_in[3];
  const float* w0    = (const float*)d_in[4];
  const float* w1    = (const float*)d_in[5];
  const float* wm    = (const float*)d_in[6];
  const float* bias  = (const float*)d_in[7];
  float* out = (float*)d_out;
  float* ws  = (float*)d_ws;

  float* S_     = ws;                                        // 8388608 f
  unsigned short* EThi = (unsigned short*)(ws + 8388608);    // 8388608 u16
  unsigned short* ETlo = (unsigned short*)(ws + 12582912);   // 8388608 u16
  float* Apart  = ws + 16777216;                             // 4 * 2097152 f
  unsigned short* qfh = (unsigned short*)(ws + 25165824);    // 2097152 u16
  unsigned short* qfl = (unsigned short*)(ws + 26214400);
  unsigned short* afh = (unsigned short*)(ws + 27262976);
  unsigned short* afl = (unsigned short*)(ws + 28311552);
  float* sub0   = ws + 29360128;                             // 65536 f
  float* qtermM = ws + 29425664;                             // 8192 f
  float* colsum = ws + 29433856;                             // 8192 f

  k_dots<<<18432, 256, 0, stream>>>(c, q, qmask, w0, w1, bias, sub0, qtermM);
  k_zero<<<32, 256, 0, stream>>>(colsum);
  k_pack_q<<<dim3(16, BB), 256, 0, stream>>>(q, qfh, qfl);
  k_score<<<dim3(8, BB), 256, 0, stream>>>(c, q, cmask, wm, sub0, qtermM, S_, EThi, ETlo, colsum);
  k_colA<<<dim3(4, BB), 512, 0, stream>>>(EThi, ETlo, c, Apart);
  k_pack_a<<<dim3(16, BB), 256, 0, stream>>>(Apart, colsum, afh, afl);
  k_out<<<dim3(32, BB), 512, 0, stream>>>(c, S_, qfh, qfl, afh, afl, out);
}